// Round 3
// baseline (91.550 us; speedup 1.0000x reference)
//
#include <hip/hip_runtime.h>

// Conv2dfft == direct 3x3 cross-correlation, pad=1, + bias (FFT grid never wraps).
// x: [32,128,32,32] f32; w: [128,128,3,3] f32; b: [128] f32; out: [32,128,32,32] f32.
// R3: single fused pack dispatch (x->NHWC-padded bf16, w->tap-major bf16), then the
// R2 implicit-GEMM conv (2 blocks/CU, XOR-swizzled LDS, 4 stage+compute phases).
// Probe: bench dur appears dominated by 2x268MB harness poison fills (~90us); this
// round removes one dispatch to test how much of dur_us is actually ours.

typedef __attribute__((ext_vector_type(8))) short bf16x8;
typedef __attribute__((ext_vector_type(4))) float f32x4;

#define N_IMG 32
#define C_IN  128
#define F_OUT 128
#define HW    32
#define HPAD  34

__device__ __forceinline__ unsigned short f2bf(float f) {
    union { float f; unsigned u; } v; v.f = f;
    unsigned r = v.u + 0x7fffu + ((v.u >> 16) & 1u);   // RNE
    return (unsigned short)(r >> 16);
}

// ---- fused pack --------------------------------------------------------------
// blocks 0..1087: x [N,C,32,32] f32 -> xp [N,34,34,C] bf16 (zero border)
// blocks 1088..1123: w [F,C,3,3] f32 -> wpk [cc 4][tap 9][f 128][ci 32] bf16
__global__ __launch_bounds__(256) void pack_kernel(const float* __restrict__ x,
                                                   const float* __restrict__ w,
                                                   unsigned short* __restrict__ xp,
                                                   unsigned short* __restrict__ wpk) {
    __shared__ unsigned short tile[C_IN * HPAD];   // [c][wp]
    const int tid = threadIdx.x;
    if (blockIdx.x < N_IMG * HPAD) {
        const int n   = blockIdx.x / HPAD;
        const int hp  = blockIdx.x - n * HPAD;
        const unsigned base_out = (unsigned)(n * HPAD + hp) * (HPAD * C_IN);
        if (hp >= 1 && hp <= 32) {
            const int h = hp - 1;
            #pragma unroll
            for (int i = 0; i < 16; ++i) {             // 4096 = 128c * 32w, coalesced reads
                int idx = tid + i * 256;
                int c = idx >> 5, ww = idx & 31;
                tile[c * HPAD + (ww + 1)] = f2bf(x[((n * C_IN + c) * HW + h) * HW + ww]);
            }
            if (tid < C_IN) { tile[tid * HPAD] = 0; tile[tid * HPAD + 33] = 0; }
            __syncthreads();
            #pragma unroll
            for (int i = 0; i < 17; ++i) {             // 4352 = 34wp * 128c, coalesced writes
                int idx = tid + i * 256;
                int wp = idx >> 7, c = idx & 127;
                xp[base_out + (unsigned)idx] = tile[c * HPAD + wp];
            }
        } else {
            #pragma unroll
            for (int i = 0; i < 17; ++i) {
                int idx = tid + i * 256;
                xp[base_out + (unsigned)idx] = 0;
            }
        }
    } else {
        // weight pack: 36 blocks x 4096 elements
        const int base = (blockIdx.x - N_IMG * HPAD) * 4096 + tid;
        #pragma unroll
        for (int i = 0; i < 16; ++i) {
            int idx = base + i * 256;                  // < 147456
            int ci = idx & 31;
            int f  = (idx >> 5) & 127;
            int u  = idx >> 12;                        // 0..35 = cc*9 + t
            int cc = u / 9;
            int t  = u - cc * 9;
            wpk[idx] = f2bf(w[(f * C_IN + cc * 32 + ci) * 9 + t]);
        }
    }
}

// ---------------- implicit-GEMM conv (unchanged from R2) ----------------------
// grid 512: (n 32) x (band 8: 4 output rows) x (f-half 2). Block 256 = 4 waves.
// Block tile 64f x 128pos; wave tile 64f x 32pos (one output row), acc[4][2].
// K = 1152 as 4 chunks of (9 taps x 32c); one stage+barrier pair per chunk.
// LDS 16B-chunk XOR swizzle: physical chunk = logical ^ ((row>>1)&3).
__global__ __launch_bounds__(256, 2) void conv_gemm_kernel(
    const unsigned short* __restrict__ xp,
    const unsigned short* __restrict__ wpk,
    const float* __restrict__ bias,
    float* __restrict__ out)
{
    __shared__ alignas(16) unsigned short lds_x[1024 * 8];   // rows 0..203 real (6 in-rows x 34), rest dump pad
    __shared__ alignas(16) unsigned short lds_a[2304 * 8];   // [tap 9][fl 64] rows x 4 chunks

    const int tid  = threadIdx.x;
    const int lane = tid & 63;
    const int wave = tid >> 6;
    const int qk   = lane >> 4;      // k-group 0..3 (logical 16B chunk)
    const int l15  = lane & 15;

    const int fh   = blockIdx.x & 1;
    const int band = (blockIdx.x >> 1) & 7;
    const int n    = blockIdx.x >> 4;
    const int f0   = fh * 64;
    const int h0   = band * 4;

    f32x4 acc[4][2];
    #pragma unroll
    for (int mi = 0; mi < 4; ++mi)
        #pragma unroll
        for (int ni = 0; ni < 2; ++ni)
            acc[mi][ni] = (f32x4){0.f, 0.f, 0.f, 0.f};

    const int a_lane = l15 * 32 + (((qk ^ (l15 >> 1)) & 3) << 3);
    int brow0[2];
    #pragma unroll
    for (int ni = 0; ni < 2; ++ni)
        brow0[ni] = wave * HPAD + ni * 16 + l15;     // + r*34+s at use site

    const unsigned short* xsrc0 = xp + (unsigned)((n * HPAD + h0) * HPAD) * C_IN;
    const unsigned short* wbase = wpk + f0 * 32;

    for (int cc = 0; cc < 4; ++cc) {
        __syncthreads();   // previous chunk's LDS reads complete before overwrite
        // ---- stage x: 1024 slots (816 real = 204 rows x 4 chunks)
        #pragma unroll
        for (int i = 0; i < 4; ++i) {
            int p = tid + i * 256;
            int row = p >> 2;  if (row > 203) row = 203;      // dump slots clamp src
            int lc = (p ^ (row >> 1)) & 3;                    // logical chunk for phys p&3
            const unsigned short* src = xsrc0 + row * C_IN + cc * 32 + lc * 8;
            __builtin_amdgcn_global_load_lds(
                (const __attribute__((address_space(1))) void*)src,
                (__attribute__((address_space(3))) void*)(&lds_x[p * 8]),
                16, 0, 0);
        }
        // ---- stage a: 2304 slots = (tap*64+fl) rows x 4 chunks
        const unsigned short* wsrc = wbase + cc * 36864;      // (cc*9 taps)*128f*32c
        #pragma unroll
        for (int j = 0; j < 9; ++j) {
            int q = tid + j * 256;
            int row = q >> 2;                                 // tap*64 + fl
            int lc = (q ^ (row >> 1)) & 3;
            const unsigned short* src = wsrc + ((row >> 6) * 4096) + ((row & 63) * 32) + lc * 8;
            __builtin_amdgcn_global_load_lds(
                (const __attribute__((address_space(1))) void*)src,
                (__attribute__((address_space(3))) void*)(&lds_a[q * 8]),
                16, 0, 0);
        }
        __syncthreads();   // drain vmcnt
        // ---- compute: 9 taps x (4mi x 2ni) MFMAs
        #pragma unroll
        for (int tap = 0; tap < 9; ++tap) {
            const int r = tap / 3, s = tap - 3 * (tap / 3);
            bf16x8 af[4], bf[2];
            #pragma unroll
            for (int mi = 0; mi < 4; ++mi)
                af[mi] = *(const bf16x8*)&lds_a[tap * 2048 + mi * 512 + a_lane];
            #pragma unroll
            for (int ni = 0; ni < 2; ++ni) {
                int row = brow0[ni] + (r * HPAD + s);
                int el  = (row << 5) + (((qk ^ (row >> 1)) & 3) << 3);
                bf[ni] = *(const bf16x8*)&lds_x[el];
            }
            #pragma unroll
            for (int mi = 0; mi < 4; ++mi)
                #pragma unroll
                for (int ni = 0; ni < 2; ++ni)
                    acc[mi][ni] = __builtin_amdgcn_mfma_f32_16x16x32_bf16(
                        af[mi], bf[ni], acc[mi][ni], 0, 0, 0);
        }
    }

    // ---- epilogue: D row (f) = qk*4 + reg, col (pos) = l15; wave owns out row h0+wave
    const int h = h0 + wave;
    #pragma unroll
    for (int mi = 0; mi < 4; ++mi) {
        const int f_base = f0 + mi * 16 + qk * 4;
        float bv[4];
        #pragma unroll
        for (int r2 = 0; r2 < 4; ++r2) bv[r2] = bias[f_base + r2];
        #pragma unroll
        for (int ni = 0; ni < 2; ++ni) {
            const int w2 = ni * 16 + l15;
            #pragma unroll
            for (int r2 = 0; r2 < 4; ++r2) {
                out[((unsigned)(n * F_OUT + f_base + r2) * HW + h) * HW + w2] =
                    acc[mi][ni][r2] + bv[r2];
            }
        }
    }
}

extern "C" void kernel_launch(void* const* d_in, const int* in_sizes, int n_in,
                              void* d_out, int out_size, void* d_ws, size_t ws_size,
                              hipStream_t stream) {
    const float* x = (const float*)d_in[0];
    const float* w = (const float*)d_in[1];
    const float* b = (const float*)d_in[2];
    float* out = (float*)d_out;

    unsigned short* xp  = (unsigned short*)d_ws;                   // 32*34*34*128 bf16
    unsigned short* wpk = xp + (size_t)N_IMG * HPAD * HPAD * C_IN; // 4*9*128*32 bf16

    pack_kernel<<<N_IMG * HPAD + 36, 256, 0, stream>>>(x, w, xp, wpk);
    conv_gemm_kernel<<<512, 256, 0, stream>>>(xp, wpk, b, out);
}